// Round 2
// baseline (458.602 us; speedup 1.0000x reference)
//
#include <hip/hip_runtime.h>
#include <math.h>

// Sizes (fixed by the problem)
#define B_SZ 8
#define L_SZ 4096
#define D_SZ 1024
#define M_SZ 64
#define ROWS (B_SZ * L_SZ)   // 32768
#define NCHUNK 64            // L / CHUNK
#define CHUNK 64

#define FMA4(acc, sc, v) { (acc).x += (sc)*(v).x; (acc).y += (sc)*(v).y; (acc).z += (sc)*(v).z; (acc).w += (sc)*(v).w; }
#define SCALE4(v, sc) { (v).x *= (sc); (v).y *= (sc); (v).z *= (sc); (v).w *= (sc); }

__device__ __forceinline__ float sigmoid_f(float z) { return 1.0f / (1.0f + __expf(-z)); }
__device__ __forceinline__ float decay_of(const float* __restrict__ dp) {
  return 0.9f + (0.999f - 0.9f) * sigmoid_f(dp[0]);
}

// ---------------- Kernel 1: fused q,k,v,gate projection ----------------
// x: (32768,1024)  Wq/Wk/Wv: (1024,64)  Wg: (1024,1)
// writes q_ws = x@Wq, a_ws = g*(x@Wk), b_ws = g*(x@Wv); g = sigmoid(x@Wg+bg)
// Tile: 64 rows x all 192 cols per block; x read exactly once from HBM.
__global__ __launch_bounds__(256) void k1_qkvg(
    const float* __restrict__ x,
    const float* __restrict__ Wq, const float* __restrict__ Wk,
    const float* __restrict__ Wv, const float* __restrict__ Wg,
    const float* __restrict__ bg,
    float* __restrict__ q_ws, float* __restrict__ a_ws, float* __restrict__ b_ws)
{
  __shared__ float As[64][17];   // +1 pad breaks bank conflicts on column reads
  __shared__ float Bq[16][64];
  __shared__ float Bk[16][64];
  __shared__ float Bv[16][64];
  __shared__ float Wgs[16];
  __shared__ float Gs[64];

  const int tid = threadIdx.x;
  const int tx = tid & 15, ty = tid >> 4;   // thread computes rows 4*ty..+3, cols 4*tx..+3
  const int row0 = blockIdx.x * 64;
  const int ar = tid >> 2, ac0 = (tid & 3) * 4;   // A-tile load coords
  const int bkk = tid >> 4, bm0 = (tid & 15) * 4; // B-tile load coords

  float4 accq[4], acck[4], accv[4];
  #pragma unroll
  for (int r = 0; r < 4; ++r) {
    accq[r] = make_float4(0,0,0,0);
    acck[r] = make_float4(0,0,0,0);
    accv[r] = make_float4(0,0,0,0);
  }
  float gacc[4] = {0.f, 0.f, 0.f, 0.f};

  for (int k0 = 0; k0 < D_SZ; k0 += 16) {
    float4 av  = *reinterpret_cast<const float4*>(&x[(size_t)(row0 + ar) * D_SZ + k0 + ac0]);
    float4 bqv = *reinterpret_cast<const float4*>(&Wq[(size_t)(k0 + bkk) * 64 + bm0]);
    float4 bkv = *reinterpret_cast<const float4*>(&Wk[(size_t)(k0 + bkk) * 64 + bm0]);
    float4 bvv = *reinterpret_cast<const float4*>(&Wv[(size_t)(k0 + bkk) * 64 + bm0]);
    float wgv = (tid < 16) ? Wg[k0 + tid] : 0.f;
    __syncthreads();  // previous iteration's compute done reading LDS
    As[ar][ac0+0] = av.x; As[ar][ac0+1] = av.y; As[ar][ac0+2] = av.z; As[ar][ac0+3] = av.w;
    *reinterpret_cast<float4*>(&Bq[bkk][bm0]) = bqv;
    *reinterpret_cast<float4*>(&Bk[bkk][bm0]) = bkv;
    *reinterpret_cast<float4*>(&Bv[bkk][bm0]) = bvv;
    if (tid < 16) Wgs[tid] = wgv;
    __syncthreads();
    #pragma unroll
    for (int kk = 0; kk < 16; ++kk) {
      float a0 = As[4*ty+0][kk];
      float a1 = As[4*ty+1][kk];
      float a2 = As[4*ty+2][kk];
      float a3 = As[4*ty+3][kk];
      float4 q4 = *reinterpret_cast<float4*>(&Bq[kk][4*tx]);
      float4 k4 = *reinterpret_cast<float4*>(&Bk[kk][4*tx]);
      float4 v4 = *reinterpret_cast<float4*>(&Bv[kk][4*tx]);
      FMA4(accq[0], a0, q4); FMA4(acck[0], a0, k4); FMA4(accv[0], a0, v4);
      FMA4(accq[1], a1, q4); FMA4(acck[1], a1, k4); FMA4(accv[1], a1, v4);
      FMA4(accq[2], a2, q4); FMA4(acck[2], a2, k4); FMA4(accv[2], a2, v4);
      FMA4(accq[3], a3, q4); FMA4(acck[3], a3, k4); FMA4(accv[3], a3, v4);
    }
    { // gate partial: this thread handles kk == tx slice of this k-step
      float w = Wgs[tx];
      #pragma unroll
      for (int r = 0; r < 4; ++r) gacc[r] += As[4*ty+r][tx] * w;
    }
  }

  // reduce gate partials across the 16 tx threads sharing the same rows
  // (tx occupies lane bits 0..3, so xor-shuffles 1,2,4,8 combine exactly them)
  #pragma unroll
  for (int r = 0; r < 4; ++r) {
    float g = gacc[r];
    g += __shfl_xor(g, 1); g += __shfl_xor(g, 2);
    g += __shfl_xor(g, 4); g += __shfl_xor(g, 8);
    if (tx == 0) Gs[4*ty + r] = sigmoid_f(g + bg[0]);
  }
  __syncthreads();

  #pragma unroll
  for (int r = 0; r < 4; ++r) {
    const int row = row0 + 4*ty + r;
    const float g = Gs[4*ty + r];
    *reinterpret_cast<float4*>(&q_ws[(size_t)row * 64 + 4*tx]) = accq[r];
    float4 ga; ga.x = g*acck[r].x; ga.y = g*acck[r].y; ga.z = g*acck[r].z; ga.w = g*acck[r].w;
    *reinterpret_cast<float4*>(&a_ws[(size_t)row * 64 + 4*tx]) = ga;
    float4 gb; gb.x = g*accv[r].x; gb.y = g*accv[r].y; gb.z = g*accv[r].z; gb.w = g*accv[r].w;
    *reinterpret_cast<float4*>(&b_ws[(size_t)row * 64 + 4*tx]) = gb;
  }
}

// ---------------- Kernel 2: per-chunk state delta ----------------
// dS[b,c] = sum_{s=0..63} decay^(63-s) * a_s (outer) b_s   -- (64x64) each
__global__ __launch_bounds__(256) void k2_delta(
    const float* __restrict__ a_ws, const float* __restrict__ b_ws,
    const float* __restrict__ dp, float* __restrict__ dS)
{
  __shared__ float Aa[64][64];
  __shared__ float Bc[64][64];
  __shared__ float pw[64];
  const int tid = threadIdx.x;
  const int bc = blockIdx.x;                       // b*64 + c
  const int rowbase = (bc >> 6) * L_SZ + (bc & 63) * CHUNK;
  const int s = tid >> 2, m0 = (tid & 3) * 16;
  #pragma unroll
  for (int j = 0; j < 4; ++j) {
    *reinterpret_cast<float4*>(&Aa[s][m0 + 4*j]) =
        *reinterpret_cast<const float4*>(&a_ws[(size_t)(rowbase + s) * 64 + m0 + 4*j]);
    *reinterpret_cast<float4*>(&Bc[s][m0 + 4*j]) =
        *reinterpret_cast<const float4*>(&b_ws[(size_t)(rowbase + s) * 64 + m0 + 4*j]);
  }
  if (tid < 64) pw[tid] = powf(decay_of(dp), (float)(63 - tid));
  __syncthreads();
  const int d0 = tid >> 2, e0 = (tid & 3) * 16;
  float4 o0 = make_float4(0,0,0,0), o1 = o0, o2 = o0, o3 = o0;
  for (int ss = 0; ss < 64; ++ss) {
    float wa = pw[ss] * Aa[ss][d0];
    float4 b0 = *reinterpret_cast<float4*>(&Bc[ss][e0+0]);
    float4 b1 = *reinterpret_cast<float4*>(&Bc[ss][e0+4]);
    float4 b2 = *reinterpret_cast<float4*>(&Bc[ss][e0+8]);
    float4 b3 = *reinterpret_cast<float4*>(&Bc[ss][e0+12]);
    FMA4(o0, wa, b0); FMA4(o1, wa, b1); FMA4(o2, wa, b2); FMA4(o3, wa, b3);
  }
  float* dst = &dS[((size_t)bc << 12) + d0 * 64 + e0];
  *reinterpret_cast<float4*>(dst + 0)  = o0;
  *reinterpret_cast<float4*>(dst + 4)  = o1;
  *reinterpret_cast<float4*>(dst + 8)  = o2;
  *reinterpret_cast<float4*>(dst + 12) = o3;
}

// ---------------- Kernel 3: elementwise scan over chunks ----------------
// Each thread owns one (b, d, e) element; scans 64 chunks.
// Sst[b,c] = state BEFORE chunk c; final state -> sfin (S_final output).
// NEEDS B*M*M = 32768 threads = 128 blocks of 256.
__global__ __launch_bounds__(256) void k3_scan(
    const float* __restrict__ dS, const float* __restrict__ dp,
    float* __restrict__ Sst, float* __restrict__ sfin)
{
  const int g = blockIdx.x * 256 + threadIdx.x;   // 0..32767
  const int b = g >> 12;
  const int de = g & 4095;
  const float dC = powf(decay_of(dp), 64.0f);
  float s = 0.f;
  for (int c = 0; c < NCHUNK; ++c) {
    const size_t idx = ((size_t)(b * 64 + c) << 12) + de;
    Sst[idx] = s;
    s = dC * s + dS[idx];
  }
  sfin[((size_t)b << 12) + de] = s;
}

// ---------------- Kernel 4: intra-chunk outputs ----------------
// out[t] = decay^(t+1) * (q_t^T S0) + sum_{s<=t} decay^(t-s) (q_t . a_s) b_s
__global__ __launch_bounds__(256) void k4_intra(
    const float* __restrict__ q_ws, const float* __restrict__ a_ws,
    const float* __restrict__ b_ws, const float* __restrict__ Sst,
    const float* __restrict__ dp, float* __restrict__ outs)
{
  __shared__ float Qs[64][68];   // padded (col reads)
  __shared__ float Ps[64][68];   // holds A^T during phase 1, then P
  __shared__ float Bs[64][64];
  __shared__ float S0s[64][64];
  __shared__ float pw[65];
  const int tid = threadIdx.x;
  const int bc = blockIdx.x;
  const int rowbase = (bc >> 6) * L_SZ + (bc & 63) * CHUNK;
  const int s = tid >> 2, m0 = (tid & 3) * 16;
  #pragma unroll
  for (int j = 0; j < 4; ++j) {
    float4 qv = *reinterpret_cast<const float4*>(&q_ws[(size_t)(rowbase + s) * 64 + m0 + 4*j]);
    Qs[s][m0+4*j+0] = qv.x; Qs[s][m0+4*j+1] = qv.y; Qs[s][m0+4*j+2] = qv.z; Qs[s][m0+4*j+3] = qv.w;
    float4 av = *reinterpret_cast<const float4*>(&a_ws[(size_t)(rowbase + s) * 64 + m0 + 4*j]);
    Ps[m0+4*j+0][s] = av.x; Ps[m0+4*j+1][s] = av.y; Ps[m0+4*j+2][s] = av.z; Ps[m0+4*j+3][s] = av.w;
    float4 bv = *reinterpret_cast<const float4*>(&b_ws[(size_t)(rowbase + s) * 64 + m0 + 4*j]);
    *reinterpret_cast<float4*>(&Bs[s][m0+4*j]) = bv;
    float4 sv = *reinterpret_cast<const float4*>(&Sst[((size_t)bc << 12) + tid*16 + 4*j]);
    *reinterpret_cast<float4*>(&(&S0s[0][0])[tid*16 + 4*j]) = sv;
  }
  if (tid < 65) pw[tid] = powf(decay_of(dp), (float)tid);
  __syncthreads();

  const int t0 = tid >> 2, c0 = (tid & 3) * 16;  // this thread: row t0, cols c0..c0+15
  // Phase 1: R[t0][c0+j] = q_t0 . a_(c0+j)   (A^T lives in Ps)
  float4 r0 = make_float4(0,0,0,0), r1 = r0, r2 = r0, r3 = r0;
  for (int m = 0; m < 64; ++m) {
    float qv = Qs[t0][m];
    float4 a0 = *reinterpret_cast<float4*>(&Ps[m][c0+0]);
    float4 a1 = *reinterpret_cast<float4*>(&Ps[m][c0+4]);
    float4 a2 = *reinterpret_cast<float4*>(&Ps[m][c0+8]);
    float4 a3 = *reinterpret_cast<float4*>(&Ps[m][c0+12]);
    FMA4(r0, qv, a0); FMA4(r1, qv, a1); FMA4(r2, qv, a2); FMA4(r3, qv, a3);
  }
  float rr[16] = {r0.x,r0.y,r0.z,r0.w, r1.x,r1.y,r1.z,r1.w,
                  r2.x,r2.y,r2.z,r2.w, r3.x,r3.y,r3.z,r3.w};
  __syncthreads();  // everyone done reading A^T
  #pragma unroll
  for (int j = 0; j < 16; ++j) {
    const int sidx = c0 + j;
    Ps[t0][sidx] = (sidx <= t0) ? rr[j] * pw[t0 - sidx] : 0.f;
  }
  __syncthreads();

  // Phase 2: out = decay^(t+1) * Q@S0 + P@B
  float4 o0 = make_float4(0,0,0,0), o1 = o0, o2 = o0, o3 = o0;
  for (int m = 0; m < 64; ++m) {
    float qv = Qs[t0][m];
    float4 v0 = *reinterpret_cast<float4*>(&S0s[m][c0+0]);
    float4 v1 = *reinterpret_cast<float4*>(&S0s[m][c0+4]);
    float4 v2 = *reinterpret_cast<float4*>(&S0s[m][c0+8]);
    float4 v3 = *reinterpret_cast<float4*>(&S0s[m][c0+12]);
    FMA4(o0, qv, v0); FMA4(o1, qv, v1); FMA4(o2, qv, v2); FMA4(o3, qv, v3);
  }
  const float dsc = pw[t0 + 1];
  SCALE4(o0, dsc); SCALE4(o1, dsc); SCALE4(o2, dsc); SCALE4(o3, dsc);
  for (int ss = 0; ss < 64; ++ss) {
    float pv = Ps[t0][ss];
    float4 b0 = *reinterpret_cast<float4*>(&Bs[ss][c0+0]);
    float4 b1 = *reinterpret_cast<float4*>(&Bs[ss][c0+4]);
    float4 b2 = *reinterpret_cast<float4*>(&Bs[ss][c0+8]);
    float4 b3 = *reinterpret_cast<float4*>(&Bs[ss][c0+12]);
    FMA4(o0, pv, b0); FMA4(o1, pv, b1); FMA4(o2, pv, b2); FMA4(o3, pv, b3);
  }
  float* dst = &outs[(size_t)(rowbase + t0) * 64 + c0];
  *reinterpret_cast<float4*>(dst + 0)  = o0;
  *reinterpret_cast<float4*>(dst + 4)  = o1;
  *reinterpret_cast<float4*>(dst + 8)  = o2;
  *reinterpret_cast<float4*>(dst + 12) = o3;
}

// ---------------- Kernel 5: output projection ----------------
// y = outs(32768x64) @ Wo(64x1024) + bo
__global__ __launch_bounds__(256) void k5_proj(
    const float* __restrict__ outs, const float* __restrict__ Wo,
    const float* __restrict__ bo, float* __restrict__ y)
{
  __shared__ float Os[64][68];
  __shared__ float Ws[64][64];
  const int tid = threadIdx.x;
  const int tx = tid & 15, ty = tid >> 4;
  const int row0 = blockIdx.x * 64;
  const int n0 = blockIdx.y * 64;
  const int s = tid >> 2, m0 = (tid & 3) * 16;
  #pragma unroll
  for (int j = 0; j < 4; ++j) {
    float4 ov = *reinterpret_cast<const float4*>(&outs[(size_t)(row0 + s) * 64 + m0 + 4*j]);
    Os[s][m0+4*j+0] = ov.x; Os[s][m0+4*j+1] = ov.y; Os[s][m0+4*j+2] = ov.z; Os[s][m0+4*j+3] = ov.w;
    float4 wv = *reinterpret_cast<const float4*>(&Wo[(size_t)s * D_SZ + n0 + m0 + 4*j]);
    *reinterpret_cast<float4*>(&Ws[s][m0+4*j]) = wv;
  }
  __syncthreads();
  float4 acc[4];
  #pragma unroll
  for (int r = 0; r < 4; ++r) acc[r] = make_float4(0,0,0,0);
  for (int kk = 0; kk < 64; ++kk) {
    float a0 = Os[4*ty+0][kk];
    float a1 = Os[4*ty+1][kk];
    float a2 = Os[4*ty+2][kk];
    float a3 = Os[4*ty+3][kk];
    float4 w = *reinterpret_cast<float4*>(&Ws[kk][4*tx]);
    FMA4(acc[0], a0, w); FMA4(acc[1], a1, w); FMA4(acc[2], a2, w); FMA4(acc[3], a3, w);
  }
  float4 bv = *reinterpret_cast<const float4*>(&bo[n0 + 4*tx]);
  #pragma unroll
  for (int r = 0; r < 4; ++r) {
    float4 res;
    res.x = acc[r].x + bv.x; res.y = acc[r].y + bv.y;
    res.z = acc[r].z + bv.z; res.w = acc[r].w + bv.w;
    *reinterpret_cast<float4*>(&y[(size_t)(row0 + 4*ty + r) * D_SZ + n0 + 4*tx]) = res;
  }
}

// ---------------- Launcher ----------------
extern "C" void kernel_launch(void* const* d_in, const int* in_sizes, int n_in,
                              void* d_out, int out_size, void* d_ws, size_t ws_size,
                              hipStream_t stream) {
  (void)in_sizes; (void)n_in; (void)out_size; (void)ws_size;
  const float* x  = (const float*)d_in[0];
  const float* Wq = (const float*)d_in[1];
  const float* Wk = (const float*)d_in[2];
  const float* Wv = (const float*)d_in[3];
  const float* Wo = (const float*)d_in[4];
  const float* bo = (const float*)d_in[5];
  const float* Wg = (const float*)d_in[6];
  const float* bg = (const float*)d_in[7];
  const float* dp = (const float*)d_in[8];

  float* y    = (float*)d_out;                       // (8,4096,1024)
  float* sfin = y + (size_t)B_SZ * L_SZ * D_SZ;      // (8,64,64)

  float* ws   = (float*)d_ws;
  const size_t SEG = (size_t)ROWS * M_SZ;            // 2,097,152 floats
  float* q_ws = ws;
  float* a_ws = q_ws + SEG;
  float* b_ws = a_ws + SEG;
  float* dS   = b_ws + SEG;   // (B*NC, 64,64)
  float* Sst  = dS   + SEG;   // chunk-start states
  float* outs = Sst  + SEG;   // (32768, 64)

  k1_qkvg<<<dim3(ROWS / 64), dim3(256), 0, stream>>>(x, Wq, Wk, Wv, Wg, bg, q_ws, a_ws, b_ws);
  k2_delta<<<dim3(B_SZ * NCHUNK), dim3(256), 0, stream>>>(a_ws, b_ws, dp, dS);
  k3_scan<<<dim3((B_SZ * M_SZ * M_SZ) / 256), dim3(256), 0, stream>>>(dS, dp, Sst, sfin);
  k4_intra<<<dim3(B_SZ * NCHUNK), dim3(256), 0, stream>>>(q_ws, a_ws, b_ws, Sst, dp, outs);
  k5_proj<<<dim3(ROWS / 64, D_SZ / 64), dim3(256), 0, stream>>>(outs, Wo, bo, y);
}

// Round 3
// 387.341 us; speedup vs baseline: 1.1840x; 1.1840x over previous
//
#include <hip/hip_runtime.h>
#include <math.h>

// Sizes (fixed by the problem)
#define B_SZ 8
#define L_SZ 4096
#define D_SZ 1024
#define M_SZ 64
#define ROWS (B_SZ * L_SZ)   // 32768
#define NCHUNK 64            // L / CHUNK
#define CHUNK 64

#define FMA4(acc, sc, v) { (acc).x += (sc)*(v).x; (acc).y += (sc)*(v).y; (acc).z += (sc)*(v).z; (acc).w += (sc)*(v).w; }
#define SCALE4(v, sc) { (v).x *= (sc); (v).y *= (sc); (v).z *= (sc); (v).w *= (sc); }

typedef __attribute__((ext_vector_type(8))) short bf16x8;
typedef __attribute__((ext_vector_type(4))) float f32x4;

__device__ __forceinline__ float sigmoid_f(float z) { return 1.0f / (1.0f + __expf(-z)); }
__device__ __forceinline__ float decay_of(const float* __restrict__ dp) {
  return 0.9f + (0.999f - 0.9f) * sigmoid_f(dp[0]);
}
// fp32 -> bf16 round-to-nearest-even
__device__ __forceinline__ unsigned short f2bf(float f) {
  unsigned int u = __float_as_uint(f);
  unsigned int r = (u + 0x7FFFu + ((u >> 16) & 1u)) >> 16;
  return (unsigned short)r;
}

// ---------------- Kernel 0: weight prep ----------------
// Wt[n][k] = W*[k][n] in bf16; n: 0-63 = Wq cols, 64-127 = Wk, 128-191 = Wv.
__global__ __launch_bounds__(256) void k0_prep(
    const float* __restrict__ Wq, const float* __restrict__ Wk,
    const float* __restrict__ Wv, unsigned short* __restrict__ Wt)
{
  const int n = blockIdx.x;
  const float* src = (n < 64) ? Wq : (n < 128) ? Wk : Wv;
  const int nc = n & 63;
  #pragma unroll
  for (int j = 0; j < 4; ++j) {
    int k = threadIdx.x + 256 * j;
    Wt[(size_t)n * D_SZ + k] = f2bf(src[(size_t)k * 64 + nc]);
  }
}

// ---------------- Kernel 1: MFMA fused q,k,v,gate projection ----------------
// Block: 128 rows x 192 cols, 4 waves (each: 32 rows x 192 cols = 2x12 frags).
// A (x) staged fp32->bf16 into LDS; B read pre-converted from Wt.
// Gate accumulated in fp32 from the original x registers.
#define K1_ROWS 128
#define K1_LDA 72   // bf16 elems/row: 64 + 8 pad -> 144B rows (16B aligned, de-aliased banks)
#define K1_LDB 72

__global__ __launch_bounds__(256, 1) void k1_qkvg_mfma(
    const float* __restrict__ x, const unsigned short* __restrict__ Wt,
    const float* __restrict__ Wg, const float* __restrict__ bg,
    float* __restrict__ q_ws, float* __restrict__ a_ws, float* __restrict__ b_ws)
{
  __shared__ __align__(16) unsigned short As[K1_ROWS * K1_LDA];
  __shared__ __align__(16) unsigned short Bs[192 * K1_LDB];
  __shared__ float Wgs[64];
  __shared__ float Gs[K1_ROWS];

  const int tid  = threadIdx.x;
  const int lane = tid & 63;
  const int w    = tid >> 6;        // wave 0..3
  const int quad = lane >> 4;
  const int l15  = lane & 15;
  const int row0 = blockIdx.x * K1_ROWS;

  const int srow = tid >> 1;        // staging row 0..127
  const int skh  = tid & 1;         // staging k-half (32 elems each)

  f32x4 acc[2][12];
  #pragma unroll
  for (int tr = 0; tr < 2; ++tr)
    #pragma unroll
    for (int tn = 0; tn < 12; ++tn)
      acc[tr][tn] = (f32x4){0.f, 0.f, 0.f, 0.f};

  float gacc = 0.f;

  for (int k0 = 0; k0 < D_SZ; k0 += 64) {
    // ---- issue global loads ----
    float4 xa[8];
    const float* xp = x + (size_t)(row0 + srow) * D_SZ + k0 + skh * 32;
    #pragma unroll
    for (int j = 0; j < 8; ++j) xa[j] = *reinterpret_cast<const float4*>(xp + 4 * j);
    uint4 bb[6];
    #pragma unroll
    for (int i = 0; i < 6; ++i) {
      int cid = tid + 256 * i;            // 0..1535 -> (n, 8k-chunk)
      int n = cid >> 3, c = cid & 7;
      bb[i] = *reinterpret_cast<const uint4*>(Wt + (size_t)n * D_SZ + k0 + 8 * c);
    }
    float4 wgv = make_float4(0, 0, 0, 0);
    if (tid < 16) wgv = *reinterpret_cast<const float4*>(Wg + k0 + 4 * tid);

    __syncthreads();   // prev iteration's frag reads done

    // ---- convert + write LDS ----
    #pragma unroll
    for (int j = 0; j < 4; ++j) {
      uint4 p;
      p.x = (unsigned)f2bf(xa[2*j].x)   | ((unsigned)f2bf(xa[2*j].y)   << 16);
      p.y = (unsigned)f2bf(xa[2*j].z)   | ((unsigned)f2bf(xa[2*j].w)   << 16);
      p.z = (unsigned)f2bf(xa[2*j+1].x) | ((unsigned)f2bf(xa[2*j+1].y) << 16);
      p.w = (unsigned)f2bf(xa[2*j+1].z) | ((unsigned)f2bf(xa[2*j+1].w) << 16);
      *reinterpret_cast<uint4*>(&As[srow * K1_LDA + skh * 32 + 8 * j]) = p;
    }
    #pragma unroll
    for (int i = 0; i < 6; ++i) {
      int cid = tid + 256 * i;
      int n = cid >> 3, c = cid & 7;
      *reinterpret_cast<uint4*>(&Bs[n * K1_LDB + 8 * c]) = bb[i];
    }
    if (tid < 16) *reinterpret_cast<float4*>(&Wgs[4 * tid]) = wgv;
    __syncthreads();

    // ---- gate partial (fp32, from held x registers) ----
    #pragma unroll
    for (int j = 0; j < 8; ++j) {
      float4 wv = *reinterpret_cast<float4*>(&Wgs[skh * 32 + 4 * j]);
      gacc += xa[j].x * wv.x + xa[j].y * wv.y + xa[j].z * wv.z + xa[j].w * wv.w;
    }

    // ---- MFMA ----
    #pragma unroll
    for (int kt = 0; kt < 2; ++kt) {
      bf16x8 af0 = *reinterpret_cast<bf16x8*>(&As[(32 * w +      l15) * K1_LDA + kt * 32 + quad * 8]);
      bf16x8 af1 = *reinterpret_cast<bf16x8*>(&As[(32 * w + 16 + l15) * K1_LDA + kt * 32 + quad * 8]);
      #pragma unroll
      for (int tn = 0; tn < 12; ++tn) {
        bf16x8 bfv = *reinterpret_cast<bf16x8*>(&Bs[(tn * 16 + l15) * K1_LDB + kt * 32 + quad * 8]);
        acc[0][tn] = __builtin_amdgcn_mfma_f32_16x16x32_bf16(af0, bfv, acc[0][tn], 0, 0, 0);
        acc[1][tn] = __builtin_amdgcn_mfma_f32_16x16x32_bf16(af1, bfv, acc[1][tn], 0, 0, 0);
      }
    }
  }

  // ---- gate finalize: pair (tid, tid^1) covers the full 1024-k dot ----
  float gfull = gacc + __shfl_xor(gacc, 1);
  if ((tid & 1) == 0) Gs[srow] = sigmoid_f(gfull + bg[0]);
  __syncthreads();

  // ---- epilogue: C row = quad*4+reg, col = lane&15 (m89-verified layout) ----
  #pragma unroll
  for (int tr = 0; tr < 2; ++tr) {
    const int rbase = 32 * w + 16 * tr + quad * 4;
    #pragma unroll
    for (int tn = 0; tn < 12; ++tn) {
      const int ncol = (tn & 3) * 16 + l15;
      float* dst = (tn < 4) ? q_ws : (tn < 8 ? a_ws : b_ws);
      #pragma unroll
      for (int r = 0; r < 4; ++r) {
        const int rl = rbase + r;
        float vv = acc[tr][tn][r];
        if (tn >= 4) vv *= Gs[rl];
        dst[(size_t)(row0 + rl) * 64 + ncol] = vv;
      }
    }
  }
}

// ---------------- Kernel 2: per-chunk state delta ----------------
__global__ __launch_bounds__(256) void k2_delta(
    const float* __restrict__ a_ws, const float* __restrict__ b_ws,
    const float* __restrict__ dp, float* __restrict__ dS)
{
  __shared__ float Aa[64][64];
  __shared__ float Bc[64][64];
  __shared__ float pw[64];
  const int tid = threadIdx.x;
  const int bc = blockIdx.x;                       // b*64 + c
  const int rowbase = (bc >> 6) * L_SZ + (bc & 63) * CHUNK;
  const int s = tid >> 2, m0 = (tid & 3) * 16;
  #pragma unroll
  for (int j = 0; j < 4; ++j) {
    *reinterpret_cast<float4*>(&Aa[s][m0 + 4*j]) =
        *reinterpret_cast<const float4*>(&a_ws[(size_t)(rowbase + s) * 64 + m0 + 4*j]);
    *reinterpret_cast<float4*>(&Bc[s][m0 + 4*j]) =
        *reinterpret_cast<const float4*>(&b_ws[(size_t)(rowbase + s) * 64 + m0 + 4*j]);
  }
  if (tid < 64) pw[tid] = powf(decay_of(dp), (float)(63 - tid));
  __syncthreads();
  const int d0 = tid >> 2, e0 = (tid & 3) * 16;
  float4 o0 = make_float4(0,0,0,0), o1 = o0, o2 = o0, o3 = o0;
  for (int ss = 0; ss < 64; ++ss) {
    float wa = pw[ss] * Aa[ss][d0];
    float4 b0 = *reinterpret_cast<float4*>(&Bc[ss][e0+0]);
    float4 b1 = *reinterpret_cast<float4*>(&Bc[ss][e0+4]);
    float4 b2 = *reinterpret_cast<float4*>(&Bc[ss][e0+8]);
    float4 b3 = *reinterpret_cast<float4*>(&Bc[ss][e0+12]);
    FMA4(o0, wa, b0); FMA4(o1, wa, b1); FMA4(o2, wa, b2); FMA4(o3, wa, b3);
  }
  float* dst = &dS[((size_t)bc << 12) + d0 * 64 + e0];
  *reinterpret_cast<float4*>(dst + 0)  = o0;
  *reinterpret_cast<float4*>(dst + 4)  = o1;
  *reinterpret_cast<float4*>(dst + 8)  = o2;
  *reinterpret_cast<float4*>(dst + 12) = o3;
}

// ---------------- Kernel 3: elementwise scan over chunks ----------------
__global__ __launch_bounds__(256) void k3_scan(
    const float* __restrict__ dS, const float* __restrict__ dp,
    float* __restrict__ Sst, float* __restrict__ sfin)
{
  const int g = blockIdx.x * 256 + threadIdx.x;   // 0..32767
  const int b = g >> 12;
  const int de = g & 4095;
  const float dC = powf(decay_of(dp), 64.0f);
  float s = 0.f;
  for (int c = 0; c < NCHUNK; ++c) {
    const size_t idx = ((size_t)(b * 64 + c) << 12) + de;
    Sst[idx] = s;
    s = dC * s + dS[idx];
  }
  sfin[((size_t)b << 12) + de] = s;
}

// ---------------- Kernel 4: intra-chunk outputs ----------------
__global__ __launch_bounds__(256) void k4_intra(
    const float* __restrict__ q_ws, const float* __restrict__ a_ws,
    const float* __restrict__ b_ws, const float* __restrict__ Sst,
    const float* __restrict__ dp, float* __restrict__ outs)
{
  __shared__ float Qs[64][68];   // padded (col reads)
  __shared__ float Ps[64][68];   // holds A^T during phase 1, then P
  __shared__ float Bs[64][64];
  __shared__ float S0s[64][64];
  __shared__ float pw[65];
  const int tid = threadIdx.x;
  const int bc = blockIdx.x;
  const int rowbase = (bc >> 6) * L_SZ + (bc & 63) * CHUNK;
  const int s = tid >> 2, m0 = (tid & 3) * 16;
  #pragma unroll
  for (int j = 0; j < 4; ++j) {
    float4 qv = *reinterpret_cast<const float4*>(&q_ws[(size_t)(rowbase + s) * 64 + m0 + 4*j]);
    Qs[s][m0+4*j+0] = qv.x; Qs[s][m0+4*j+1] = qv.y; Qs[s][m0+4*j+2] = qv.z; Qs[s][m0+4*j+3] = qv.w;
    float4 av = *reinterpret_cast<const float4*>(&a_ws[(size_t)(rowbase + s) * 64 + m0 + 4*j]);
    Ps[m0+4*j+0][s] = av.x; Ps[m0+4*j+1][s] = av.y; Ps[m0+4*j+2][s] = av.z; Ps[m0+4*j+3][s] = av.w;
    float4 bv = *reinterpret_cast<const float4*>(&b_ws[(size_t)(rowbase + s) * 64 + m0 + 4*j]);
    *reinterpret_cast<float4*>(&Bs[s][m0+4*j]) = bv;
    float4 sv = *reinterpret_cast<const float4*>(&Sst[((size_t)bc << 12) + tid*16 + 4*j]);
    *reinterpret_cast<float4*>(&(&S0s[0][0])[tid*16 + 4*j]) = sv;
  }
  if (tid < 65) pw[tid] = powf(decay_of(dp), (float)tid);
  __syncthreads();

  const int t0 = tid >> 2, c0 = (tid & 3) * 16;  // this thread: row t0, cols c0..c0+15
  float4 r0 = make_float4(0,0,0,0), r1 = r0, r2 = r0, r3 = r0;
  for (int m = 0; m < 64; ++m) {
    float qv = Qs[t0][m];
    float4 a0 = *reinterpret_cast<float4*>(&Ps[m][c0+0]);
    float4 a1 = *reinterpret_cast<float4*>(&Ps[m][c0+4]);
    float4 a2 = *reinterpret_cast<float4*>(&Ps[m][c0+8]);
    float4 a3 = *reinterpret_cast<float4*>(&Ps[m][c0+12]);
    FMA4(r0, qv, a0); FMA4(r1, qv, a1); FMA4(r2, qv, a2); FMA4(r3, qv, a3);
  }
  float rr[16] = {r0.x,r0.y,r0.z,r0.w, r1.x,r1.y,r1.z,r1.w,
                  r2.x,r2.y,r2.z,r2.w, r3.x,r3.y,r3.z,r3.w};
  __syncthreads();  // everyone done reading A^T
  #pragma unroll
  for (int j = 0; j < 16; ++j) {
    const int sidx = c0 + j;
    Ps[t0][sidx] = (sidx <= t0) ? rr[j] * pw[t0 - sidx] : 0.f;
  }
  __syncthreads();

  float4 o0 = make_float4(0,0,0,0), o1 = o0, o2 = o0, o3 = o0;
  for (int m = 0; m < 64; ++m) {
    float qv = Qs[t0][m];
    float4 v0 = *reinterpret_cast<float4*>(&S0s[m][c0+0]);
    float4 v1 = *reinterpret_cast<float4*>(&S0s[m][c0+4]);
    float4 v2 = *reinterpret_cast<float4*>(&S0s[m][c0+8]);
    float4 v3 = *reinterpret_cast<float4*>(&S0s[m][c0+12]);
    FMA4(o0, qv, v0); FMA4(o1, qv, v1); FMA4(o2, qv, v2); FMA4(o3, qv, v3);
  }
  const float dsc = pw[t0 + 1];
  SCALE4(o0, dsc); SCALE4(o1, dsc); SCALE4(o2, dsc); SCALE4(o3, dsc);
  for (int ss = 0; ss < 64; ++ss) {
    float pv = Ps[t0][ss];
    float4 b0 = *reinterpret_cast<float4*>(&Bs[ss][c0+0]);
    float4 b1 = *reinterpret_cast<float4*>(&Bs[ss][c0+4]);
    float4 b2 = *reinterpret_cast<float4*>(&Bs[ss][c0+8]);
    float4 b3 = *reinterpret_cast<float4*>(&Bs[ss][c0+12]);
    FMA4(o0, pv, b0); FMA4(o1, pv, b1); FMA4(o2, pv, b2); FMA4(o3, pv, b3);
  }
  float* dst = &outs[(size_t)(rowbase + t0) * 64 + c0];
  *reinterpret_cast<float4*>(dst + 0)  = o0;
  *reinterpret_cast<float4*>(dst + 4)  = o1;
  *reinterpret_cast<float4*>(dst + 8)  = o2;
  *reinterpret_cast<float4*>(dst + 12) = o3;
}

// ---------------- Kernel 5: output projection ----------------
__global__ __launch_bounds__(256) void k5_proj(
    const float* __restrict__ outs, const float* __restrict__ Wo,
    const float* __restrict__ bo, float* __restrict__ y)
{
  __shared__ float Os[64][68];
  __shared__ float Ws[64][64];
  const int tid = threadIdx.x;
  const int tx = tid & 15, ty = tid >> 4;
  const int row0 = blockIdx.x * 64;
  const int n0 = blockIdx.y * 64;
  const int s = tid >> 2, m0 = (tid & 3) * 16;
  #pragma unroll
  for (int j = 0; j < 4; ++j) {
    float4 ov = *reinterpret_cast<const float4*>(&outs[(size_t)(row0 + s) * 64 + m0 + 4*j]);
    Os[s][m0+4*j+0] = ov.x; Os[s][m0+4*j+1] = ov.y; Os[s][m0+4*j+2] = ov.z; Os[s][m0+4*j+3] = ov.w;
    float4 wv = *reinterpret_cast<const float4*>(&Wo[(size_t)s * D_SZ + n0 + m0 + 4*j]);
    *reinterpret_cast<float4*>(&Ws[s][m0+4*j]) = wv;
  }
  __syncthreads();
  float4 acc[4];
  #pragma unroll
  for (int r = 0; r < 4; ++r) acc[r] = make_float4(0,0,0,0);
  for (int kk = 0; kk < 64; ++kk) {
    float a0 = Os[4*ty+0][kk];
    float a1 = Os[4*ty+1][kk];
    float a2 = Os[4*ty+2][kk];
    float a3 = Os[4*ty+3][kk];
    float4 w = *reinterpret_cast<float4*>(&Ws[kk][4*tx]);
    FMA4(acc[0], a0, w); FMA4(acc[1], a1, w); FMA4(acc[2], a2, w); FMA4(acc[3], a3, w);
  }
  float4 bv = *reinterpret_cast<const float4*>(&bo[n0 + 4*tx]);
  #pragma unroll
  for (int r = 0; r < 4; ++r) {
    float4 res;
    res.x = acc[r].x + bv.x; res.y = acc[r].y + bv.y;
    res.z = acc[r].z + bv.z; res.w = acc[r].w + bv.w;
    *reinterpret_cast<float4*>(&y[(size_t)(row0 + 4*ty + r) * D_SZ + n0 + 4*tx]) = res;
  }
}

// ---------------- Launcher ----------------
extern "C" void kernel_launch(void* const* d_in, const int* in_sizes, int n_in,
                              void* d_out, int out_size, void* d_ws, size_t ws_size,
                              hipStream_t stream) {
  (void)in_sizes; (void)n_in; (void)out_size; (void)ws_size;
  const float* x  = (const float*)d_in[0];
  const float* Wq = (const float*)d_in[1];
  const float* Wk = (const float*)d_in[2];
  const float* Wv = (const float*)d_in[3];
  const float* Wo = (const float*)d_in[4];
  const float* bo = (const float*)d_in[5];
  const float* Wg = (const float*)d_in[6];
  const float* bg = (const float*)d_in[7];
  const float* dp = (const float*)d_in[8];

  float* y    = (float*)d_out;                       // (8,4096,1024)
  float* sfin = y + (size_t)B_SZ * L_SZ * D_SZ;      // (8,64,64)

  float* ws   = (float*)d_ws;
  const size_t SEG = (size_t)ROWS * M_SZ;            // 2,097,152 floats
  float* q_ws = ws;
  float* a_ws = q_ws + SEG;
  float* b_ws = a_ws + SEG;
  float* dS   = b_ws + SEG;   // (B*NC, 64,64)
  float* Sst  = dS   + SEG;   // chunk-start states
  float* outs = Sst  + SEG;   // (32768, 64)
  // Wt (bf16 192x1024 = 384KB) aliases the head of `outs`: dead after k1
  // reads it, before k4 writes outs. Rewritten every call (ws re-poisoned).
  unsigned short* Wt = (unsigned short*)outs;

  k0_prep<<<dim3(192), dim3(256), 0, stream>>>(Wq, Wk, Wv, Wt);
  k1_qkvg_mfma<<<dim3(ROWS / K1_ROWS), dim3(256), 0, stream>>>(x, Wt, Wg, bg, q_ws, a_ws, b_ws);
  k2_delta<<<dim3(B_SZ * NCHUNK), dim3(256), 0, stream>>>(a_ws, b_ws, dp, dS);
  k3_scan<<<dim3((B_SZ * M_SZ * M_SZ) / 256), dim3(256), 0, stream>>>(dS, dp, Sst, sfin);
  k4_intra<<<dim3(B_SZ * NCHUNK), dim3(256), 0, stream>>>(q_ws, a_ws, b_ws, Sst, dp, outs);
  k5_proj<<<dim3(ROWS / 64, D_SZ / 64), dim3(256), 0, stream>>>(outs, Wo, bo, y);
}